// Round 7
// baseline (355.372 us; speedup 1.0000x reference)
//
#include <hip/hip_runtime.h>
#include <math.h>

#define F 128
#define THREEF 384
#define N_RBF 20
#define CUTOFF 5.0f
#define CAP 64

// ---------------------------------------------------------------------------
// Kernel 1: phi = silu(h @ W1 + b1) @ W2 + b2, stored as 3 planes [c][node][f]
// 32 nodes/block (halves per-node W1/W2 L2 traffic vs 16), 256 threads.
// Register discipline: preload w per k4 (8/12 regs), process rows in halves.
// ---------------------------------------------------------------------------
__global__ __launch_bounds__(256, 2) void mlp_kernel(
    const float* __restrict__ h, const float* __restrict__ W1,
    const float* __restrict__ b1, const float* __restrict__ W2,
    const float* __restrict__ b2, float* __restrict__ phi, int N)
{
    __shared__ float sh_h[32 * F];
    __shared__ float sh_t[32 * F];
    const int tid   = threadIdx.x;
    const int node0 = blockIdx.x * 32;

    {   // 32x128 floats = 1024 float4
        const float4* src = (const float4*)(h + (size_t)node0 * F);
        float4* dst = (float4*)sh_h;
        #pragma unroll
        for (int i = 0; i < 4; ++i)
            dst[tid + i * 256] = src[tid + i * 256];
    }
    __syncthreads();

    const int j2 = tid & 63;          // 2 cols (G1) / 3+3 cols (G2)
    const int r0 = (tid >> 6) * 8;    // 4 groups x 8 rows = 32 nodes

    // ---- GEMM1 + silu: 8 rows x 2 cols
    {
        float acc[8][2];
        const float bb0 = b1[j2], bb1 = b1[j2 + 64];
        #pragma unroll
        for (int r = 0; r < 8; ++r) { acc[r][0] = bb0; acc[r][1] = bb1; }
        for (int k4 = 0; k4 < F; k4 += 4) {
            float w[4][2];
            #pragma unroll
            for (int kk = 0; kk < 4; ++kk) {
                w[kk][0] = W1[(k4 + kk) * F + j2];
                w[kk][1] = W1[(k4 + kk) * F + j2 + 64];
            }
            #pragma unroll
            for (int half = 0; half < 2; ++half) {
                float4 a[4];
                #pragma unroll
                for (int r = 0; r < 4; ++r)
                    a[r] = *(const float4*)&sh_h[(r0 + half * 4 + r) * F + k4];
                #pragma unroll
                for (int kk = 0; kk < 4; ++kk)
                    #pragma unroll
                    for (int r = 0; r < 4; ++r) {
                        const float av = ((const float*)&a[r])[kk];
                        acc[half * 4 + r][0] = fmaf(av, w[kk][0], acc[half * 4 + r][0]);
                        acc[half * 4 + r][1] = fmaf(av, w[kk][1], acc[half * 4 + r][1]);
                    }
            }
        }
        #pragma unroll
        for (int r = 0; r < 8; ++r) {
            const float x0 = acc[r][0], x1 = acc[r][1];
            sh_t[(r0 + r) * F + j2]      = x0 / (1.0f + __expf(-x0));
            sh_t[(r0 + r) * F + j2 + 64] = x1 / (1.0f + __expf(-x1));
        }
    }
    __syncthreads();

    // ---- GEMM2: two passes of 3 cols (8 rows each)
    #pragma unroll
    for (int pass = 0; pass < 2; ++pass) {
        const int c0 = pass * 3;
        float acc[8][3];
        #pragma unroll
        for (int c = 0; c < 3; ++c) {
            const float bb = b2[j2 + (c0 + c) * 64];
            #pragma unroll
            for (int r = 0; r < 8; ++r) acc[r][c] = bb;
        }
        for (int k4 = 0; k4 < F; k4 += 4) {
            float w[4][3];
            #pragma unroll
            for (int kk = 0; kk < 4; ++kk)
                #pragma unroll
                for (int c = 0; c < 3; ++c)
                    w[kk][c] = W2[(k4 + kk) * THREEF + j2 + (c0 + c) * 64];
            #pragma unroll
            for (int half = 0; half < 2; ++half) {
                float4 a[4];
                #pragma unroll
                for (int r = 0; r < 4; ++r)
                    a[r] = *(const float4*)&sh_t[(r0 + half * 4 + r) * F + k4];
                #pragma unroll
                for (int kk = 0; kk < 4; ++kk)
                    #pragma unroll
                    for (int r = 0; r < 4; ++r) {
                        const float av = ((const float*)&a[r])[kk];
                        #pragma unroll
                        for (int c = 0; c < 3; ++c)
                            acc[half * 4 + r][c] =
                                fmaf(av, w[kk][c], acc[half * 4 + r][c]);
                    }
            }
        }
        #pragma unroll
        for (int r = 0; r < 8; ++r)
            #pragma unroll
            for (int c = 0; c < 3; ++c) {
                const int col = j2 + (c0 + c) * 64;
                const int p   = col >> 7;
                const int fc  = col & 127;
                phi[(size_t)p * N * F + (size_t)(node0 + r0 + r) * F + fc] = acc[r][c];
            }
    }
}

// ---------------------------------------------------------------------------
// Build: slot via atomic; eid scatter (4B); pack linear by edge (coalesced).
// pack[e] = {s1, 2cos(x), fcut, ux, uy, uz, src_bits, 0}
// ---------------------------------------------------------------------------
__global__ __launch_bounds__(256) void build_kernel(
    const float* __restrict__ d_ij, const float* __restrict__ unit_r,
    const int* __restrict__ nbrs, int* __restrict__ cnt,
    int* __restrict__ eid, float* __restrict__ pack, int E)
{
    int e = blockIdx.x * 256 + threadIdx.x;
    if (e >= E) return;
    const int dst = nbrs[2 * e];
    const int src = nbrs[2 * e + 1];
    const int slot = atomicAdd(&cnt[dst], 1);
    if (slot < CAP) eid[dst * CAP + slot] = e;

    const float d = d_ij[e];
    const float x = (float)M_PI * d * (1.0f / CUTOFF);
    float sx, cx;
    __sincosf(x, &sx, &cx);
    const float fcut = (d < CUTOFF) ? 0.5f * (cx + 1.0f) : 0.0f;
    float4 q0, q1;
    q0.x = sx * fcut / d;     // rbff_1; recurrence preserves the fcut/d scale
    q0.y = 2.0f * cx;
    q0.z = fcut;
    q0.w = unit_r[3 * e + 0];
    q1.x = unit_r[3 * e + 1];
    q1.y = unit_r[3 * e + 2];
    q1.z = __int_as_float(src);
    q1.w = 0.0f;
    float4* pk = (float4*)(pack + (size_t)e * 8);
    pk[0] = q0;
    pk[1] = q1;
}

// ---------------------------------------------------------------------------
// Gather: 256 threads = 2 nodes/block, thread = feature f of its node.
// Wr in LDS (30 KB, conflict-free), 4-edge inner tile amortizes each ds_read
// over 12 FMAs. Per-edge uniforms via wave-uniform loads -> SGPRs.
// VGPR live set ~40 (a[4][3] + rc/rp[4] + acc) -- sized for this allocator.
// ---------------------------------------------------------------------------
__global__ __launch_bounds__(256, 2) void gather_kernel(
    const float* __restrict__ phi,       // 3 planes of (N,128)
    const float* __restrict__ v_i,       // (N,128,3)
    const float* __restrict__ Wr,        // (20,384)
    const float* __restrict__ br,        // (384)
    const int*   __restrict__ cnt,       // (N)
    const int*   __restrict__ eid,       // (N,CAP)
    const float* __restrict__ pack,      // (E,8)
    float* __restrict__ dh,              // (N,128)
    float* __restrict__ dv,              // (N,128,3)
    int N)
{
    __shared__ float sWr[N_RBF * THREEF];   // 30720 B

    const int tid = threadIdx.x;
    {   // cooperative load of Wr: 7680 floats = 1920 float4
        float4* dws = (float4*)sWr;
        const float4* wsrc = (const float4*)Wr;
        #pragma unroll
        for (int i = 0; i < 8; ++i) {
            const int idx = tid + i * 256;
            if (idx < N_RBF * THREEF / 4) dws[idx] = wsrc[idx];
        }
    }
    __syncthreads();

    const int node = blockIdx.x * 2 + (tid >> 7);
    const int f    = tid & 127;

    const float br0 = br[f], br1 = br[f + 128], br2 = br[f + 256];

    const int deg0 = cnt[node];
    const int deg  = deg0 < CAP ? deg0 : CAP;
    const int* my_eid = eid + node * CAP;

    const float* phi0 = phi;
    const float* phi1 = phi + (size_t)N * F;
    const float* phi2 = phi + (size_t)2 * N * F;
    const float* wf   = sWr + f;    // sWr[n*384 + f] : lane-consecutive, no conflicts

    float dh_acc = 0.0f, dv0 = 0.0f, dv1 = 0.0f, dv2 = 0.0f;

    for (int i0 = 0; i0 < deg; i0 += 4) {
        // per-edge uniform data -> scalar registers
        float s1[4], twoc[4], fcut[4], ux[4], uy[4], uz[4];
        int   srcs[4];
        #pragma unroll
        for (int j = 0; j < 4; ++j) {
            const int idx = i0 + j;
            const int e = __builtin_amdgcn_readfirstlane(
                              my_eid[idx < deg ? idx : i0]);
            const float* pkj = pack + (size_t)e * 8;
            float s  = pkj[0];
            twoc[j]  = pkj[1];
            float fc = pkj[2];
            ux[j]    = pkj[3];
            uy[j]    = pkj[4];
            uz[j]    = pkj[5];
            srcs[j]  = __builtin_amdgcn_readfirstlane(
                           __float_as_int(pkj[6]));
            if (idx >= deg) { s = 0.0f; fc = 0.0f; }
            s1[j] = s;
            fcut[j] = fc;
        }

        float a0[4], a1[4], a2[4], rp[4], rc[4];
        #pragma unroll
        for (int j = 0; j < 4; ++j) {
            a0[j] = br0 * fcut[j];
            a1[j] = br1 * fcut[j];
            a2[j] = br2 * fcut[j];
            rp[j] = 0.0f;
            rc[j] = s1[j];
        }

        #pragma unroll
        for (int n = 0; n < N_RBF; ++n) {
            const float w0 = wf[n * THREEF];
            const float w1 = wf[n * THREEF + 128];
            const float w2 = wf[n * THREEF + 256];
            #pragma unroll
            for (int j = 0; j < 4; ++j) {
                a0[j] = fmaf(rc[j], w0, a0[j]);
                a1[j] = fmaf(rc[j], w1, a1[j]);
                a2[j] = fmaf(rc[j], w2, a2[j]);
                const float rn = fmaf(twoc[j], rc[j], -rp[j]);
                rp[j] = rc[j];
                rc[j] = rn;
            }
        }

        #pragma unroll
        for (int j = 0; j < 4; ++j) {
            const int src = srcs[j];
            const float f1 = phi0[(size_t)src * F + f] * a0[j];
            const float f2 = phi1[(size_t)src * F + f] * a1[j];
            const float f3 = phi2[(size_t)src * F + f] * a2[j];

            dh_acc += f3;

            const float* vs = v_i + (size_t)src * THREEF + 3 * f;
            dv0 = fmaf(f1, ux[j], fmaf(f2, vs[0], dv0));
            dv1 = fmaf(f1, uy[j], fmaf(f2, vs[1], dv1));
            dv2 = fmaf(f1, uz[j], fmaf(f2, vs[2], dv2));
        }
    }

    dh[(size_t)node * F + f] = dh_acc;
    float* dvp = dv + (size_t)node * THREEF + 3 * f;
    dvp[0] = dv0;
    dvp[1] = dv1;
    dvp[2] = dv2;
}

extern "C" void kernel_launch(void* const* d_in, const int* in_sizes, int n_in,
                              void* d_out, int out_size, void* d_ws, size_t ws_size,
                              hipStream_t stream) {
    const float* h_i    = (const float*)d_in[0];
    const float* v_i    = (const float*)d_in[1];
    const float* d_ij   = (const float*)d_in[2];
    const float* unit_r = (const float*)d_in[3];
    const int*   nbrs   = (const int*)  d_in[4];
    const float* W1     = (const float*)d_in[5];
    const float* b1     = (const float*)d_in[6];
    const float* W2     = (const float*)d_in[7];
    const float* b2     = (const float*)d_in[8];
    const float* Wr     = (const float*)d_in[9];
    const float* br     = (const float*)d_in[10];

    const int N = in_sizes[0] / F;       // 20000
    const int E = in_sizes[2];           // 320000

    float* dh = (float*)d_out;              // (N,128)
    float* dv = dh + (size_t)N * F;         // (N,128,3)

    // workspace: phi (3*N*128) | pack (E*8) | cnt (N) | eid (N*CAP)
    float* phi  = (float*)d_ws;
    float* pack = phi + (size_t)3 * N * F;
    int*   cnt  = (int*)(pack + (size_t)E * 8);
    int*   eid  = cnt + N;

    hipMemsetAsync(cnt, 0, (size_t)N * sizeof(int), stream);

    mlp_kernel<<<(N + 31) / 32, 256, 0, stream>>>(h_i, W1, b1, W2, b2, phi, N);
    build_kernel<<<(E + 255) / 256, 256, 0, stream>>>(d_ij, unit_r, nbrs, cnt,
                                                      eid, pack, E);
    gather_kernel<<<N / 2, 256, 0, stream>>>(phi, v_i, Wr, br, cnt, eid, pack,
                                             dh, dv, N);
}

// Round 8
// 310.833 us; speedup vs baseline: 1.1433x; 1.1433x over previous
//
#include <hip/hip_runtime.h>
#include <math.h>

#define F 128
#define THREEF 384
#define N_RBF 20
#define CUTOFF 5.0f
#define CAP 64

// ---------------------------------------------------------------------------
// Kernel 1: phi = silu(h @ W1 + b1) @ W2 + b2, stored as 3 planes [c][node][f]
// (R5 known-good version)
// ---------------------------------------------------------------------------
__global__ __launch_bounds__(256) void mlp_kernel(
    const float* __restrict__ h, const float* __restrict__ W1,
    const float* __restrict__ b1, const float* __restrict__ W2,
    const float* __restrict__ b2, float* __restrict__ phi, int N)
{
    __shared__ float sh_h[16 * F];
    __shared__ float sh_t[16 * F];
    const int tid   = threadIdx.x;
    const int node0 = blockIdx.x * 16;

    {
        const float4* src = (const float4*)(h + (size_t)node0 * F);
        float4* dst = (float4*)sh_h;
        dst[tid]       = src[tid];
        dst[tid + 256] = src[tid + 256];
    }
    __syncthreads();

    const int j2 = tid & 63;
    const int r0 = (tid >> 6) * 4;

    {
        float acc[4][2];
        const float bb0 = b1[j2], bb1 = b1[j2 + 64];
        #pragma unroll
        for (int r = 0; r < 4; ++r) { acc[r][0] = bb0; acc[r][1] = bb1; }
        for (int k4 = 0; k4 < F; k4 += 4) {
            float4 a[4];
            #pragma unroll
            for (int r = 0; r < 4; ++r)
                a[r] = *(const float4*)&sh_h[(r0 + r) * F + k4];
            #pragma unroll
            for (int kk = 0; kk < 4; ++kk) {
                const float w0  = W1[(k4 + kk) * F + j2];
                const float w1v = W1[(k4 + kk) * F + j2 + 64];
                #pragma unroll
                for (int r = 0; r < 4; ++r) {
                    const float av = ((const float*)&a[r])[kk];
                    acc[r][0] = fmaf(av, w0,  acc[r][0]);
                    acc[r][1] = fmaf(av, w1v, acc[r][1]);
                }
            }
        }
        #pragma unroll
        for (int r = 0; r < 4; ++r) {
            const float x0 = acc[r][0], x1 = acc[r][1];
            sh_t[(r0 + r) * F + j2]      = x0 / (1.0f + __expf(-x0));
            sh_t[(r0 + r) * F + j2 + 64] = x1 / (1.0f + __expf(-x1));
        }
    }
    __syncthreads();

    {
        float acc[4][6];
        #pragma unroll
        for (int c = 0; c < 6; ++c) {
            const float bb = b2[j2 + c * 64];
            #pragma unroll
            for (int r = 0; r < 4; ++r) acc[r][c] = bb;
        }
        for (int k4 = 0; k4 < F; k4 += 4) {
            float4 a[4];
            #pragma unroll
            for (int r = 0; r < 4; ++r)
                a[r] = *(const float4*)&sh_t[(r0 + r) * F + k4];
            #pragma unroll
            for (int kk = 0; kk < 4; ++kk) {
                float w[6];
                #pragma unroll
                for (int c = 0; c < 6; ++c)
                    w[c] = W2[(k4 + kk) * THREEF + j2 + c * 64];
                #pragma unroll
                for (int r = 0; r < 4; ++r) {
                    const float av = ((const float*)&a[r])[kk];
                    #pragma unroll
                    for (int c = 0; c < 6; ++c)
                        acc[r][c] = fmaf(av, w[c], acc[r][c]);
                }
            }
        }
        #pragma unroll
        for (int r = 0; r < 4; ++r) {
            #pragma unroll
            for (int c = 0; c < 6; ++c) {
                const int col = j2 + c * 64;
                const int p   = col >> 7;
                const int fc  = col & 127;
                phi[(size_t)p * N * F + (size_t)(node0 + r0 + r) * F + fc] = acc[r][c];
            }
        }
    }
}

// ---------------------------------------------------------------------------
// WrT: chunked transpose of Wr for coalesced float4 access in gather.
// WrT[((n4*3 + c)*128 + f)*4 + k] = Wr[(4*n4+k)*384 + c*128 + f]
// 1920 threads, one float4 each.
// ---------------------------------------------------------------------------
__global__ __launch_bounds__(256) void wrt_kernel(
    const float* __restrict__ Wr, float* __restrict__ WrT)
{
    const int idx = blockIdx.x * 256 + threadIdx.x;   // 0 .. 1919
    if (idx >= 5 * 3 * 128) return;
    const int f  = idx & 127;
    const int c  = (idx >> 7) % 3;
    const int n4 = idx / (3 * 128);
    float4 v;
    v.x = Wr[(4 * n4 + 0) * THREEF + c * 128 + f];
    v.y = Wr[(4 * n4 + 1) * THREEF + c * 128 + f];
    v.z = Wr[(4 * n4 + 2) * THREEF + c * 128 + f];
    v.w = Wr[(4 * n4 + 3) * THREEF + c * 128 + f];
    ((float4*)WrT)[idx] = v;
}

// ---------------------------------------------------------------------------
// Build: slot via atomic; eid scatter (4B); pack linear by edge (coalesced).
// pack[e] = {s1, 2cos(x), fcut, ux, uy, uz, src_bits, 0}
// ---------------------------------------------------------------------------
__global__ __launch_bounds__(256) void build_kernel(
    const float* __restrict__ d_ij, const float* __restrict__ unit_r,
    const int* __restrict__ nbrs, int* __restrict__ cnt,
    int* __restrict__ eid, float* __restrict__ pack, int E)
{
    int e = blockIdx.x * 256 + threadIdx.x;
    if (e >= E) return;
    const int2 nb = ((const int2*)nbrs)[e];
    const int dst = nb.x;
    const int src = nb.y;
    const int slot = atomicAdd(&cnt[dst], 1);
    if (slot < CAP) eid[dst * CAP + slot] = e;

    const float d = d_ij[e];
    const float x = (float)M_PI * d * (1.0f / CUTOFF);
    float sx, cx;
    __sincosf(x, &sx, &cx);
    const float fcut = (d < CUTOFF) ? 0.5f * (cx + 1.0f) : 0.0f;
    float4 q0, q1;
    q0.x = sx * fcut / d;     // rbff_1; recurrence preserves the fcut/d scale
    q0.y = 2.0f * cx;
    q0.z = fcut;
    q0.w = unit_r[3 * e + 0];
    q1.x = unit_r[3 * e + 1];
    q1.y = unit_r[3 * e + 2];
    q1.z = __int_as_float(src);
    q1.w = 0.0f;
    float4* pk = (float4*)(pack + (size_t)e * 8);
    pk[0] = q0;
    pk[1] = q1;
}

// ---------------------------------------------------------------------------
// Gather (R5 structure): block = 1 node x 128 threads, thread = feature f.
// n-loop in 5 chunks of 4; each chunk does 3 coalesced float4 WrT loads.
// 15 wave-loads/edge for weights instead of 60 strided dwords.
// ---------------------------------------------------------------------------
__global__ __launch_bounds__(128) void gather_kernel(
    const float* __restrict__ phi,       // 3 planes of (N,128)
    const float* __restrict__ v_i,       // (N,128,3)
    const float* __restrict__ WrT,       // (5,3,128,4) chunked transpose
    const float* __restrict__ br,        // (384)
    const int*   __restrict__ cnt,       // (N)
    const int*   __restrict__ eid,       // (N,CAP)
    const float* __restrict__ pack,      // (E,8)
    float* __restrict__ dh,              // (N,128)
    float* __restrict__ dv,              // (N,128,3)
    int N)
{
    const int node = blockIdx.x;
    const int f    = threadIdx.x;

    const float br0 = br[f], br1 = br[f + 128], br2 = br[f + 256];

    const int deg0 = cnt[node];
    const int deg  = deg0 < CAP ? deg0 : CAP;
    const int* my_eid = eid + node * CAP;

    const float* phi0 = phi;
    const float* phi1 = phi + (size_t)N * F;
    const float* phi2 = phi + (size_t)2 * N * F;
    const float4* wT  = (const float4*)WrT;   // wT[(n4*3 + c)*128 + f]

    float dh_acc = 0.0f, dv0 = 0.0f, dv1 = 0.0f, dv2 = 0.0f;

    for (int i = 0; i < deg; ++i) {
        const int e = __builtin_amdgcn_readfirstlane(my_eid[i]);
        const float* pk = pack + (size_t)e * 8;
        const float s1   = pk[0];
        const float twoc = pk[1];
        const float fcut = pk[2];
        const float ux   = pk[3];
        const float uy   = pk[4];
        const float uz   = pk[5];
        const int src = __builtin_amdgcn_readfirstlane(__float_as_int(pk[6]));

        float a0 = br0 * fcut, a1 = br1 * fcut, a2 = br2 * fcut;
        float rp = 0.0f, rc = s1;
        #pragma unroll
        for (int n4 = 0; n4 < 5; ++n4) {
            const float4 w0 = wT[(n4 * 3 + 0) * 128 + f];
            const float4 w1 = wT[(n4 * 3 + 1) * 128 + f];
            const float4 w2 = wT[(n4 * 3 + 2) * 128 + f];
            #pragma unroll
            for (int k = 0; k < 4; ++k) {
                const float wa = ((const float*)&w0)[k];
                const float wb = ((const float*)&w1)[k];
                const float wc = ((const float*)&w2)[k];
                a0 = fmaf(rc, wa, a0);
                a1 = fmaf(rc, wb, a1);
                a2 = fmaf(rc, wc, a2);
                const float rn = fmaf(twoc, rc, -rp);
                rp = rc;
                rc = rn;
            }
        }

        const float f1 = phi0[(size_t)src * F + f] * a0;
        const float f2 = phi1[(size_t)src * F + f] * a1;
        const float f3 = phi2[(size_t)src * F + f] * a2;

        dh_acc += f3;

        const float* vs = v_i + (size_t)src * THREEF + 3 * f;
        dv0 = fmaf(f1, ux, fmaf(f2, vs[0], dv0));
        dv1 = fmaf(f1, uy, fmaf(f2, vs[1], dv1));
        dv2 = fmaf(f1, uz, fmaf(f2, vs[2], dv2));
    }

    dh[(size_t)node * F + f] = dh_acc;
    float* dvp = dv + (size_t)node * THREEF + 3 * f;
    dvp[0] = dv0;
    dvp[1] = dv1;
    dvp[2] = dv2;
}

extern "C" void kernel_launch(void* const* d_in, const int* in_sizes, int n_in,
                              void* d_out, int out_size, void* d_ws, size_t ws_size,
                              hipStream_t stream) {
    const float* h_i    = (const float*)d_in[0];
    const float* v_i    = (const float*)d_in[1];
    const float* d_ij   = (const float*)d_in[2];
    const float* unit_r = (const float*)d_in[3];
    const int*   nbrs   = (const int*)  d_in[4];
    const float* W1     = (const float*)d_in[5];
    const float* b1     = (const float*)d_in[6];
    const float* W2     = (const float*)d_in[7];
    const float* b2     = (const float*)d_in[8];
    const float* Wr     = (const float*)d_in[9];
    const float* br     = (const float*)d_in[10];

    const int N = in_sizes[0] / F;       // 20000
    const int E = in_sizes[2];           // 320000

    float* dh = (float*)d_out;              // (N,128)
    float* dv = dh + (size_t)N * F;         // (N,128,3)

    // workspace: phi (3*N*128) | pack (E*8) | WrT (7680) | cnt (N) | eid (N*CAP)
    float* phi  = (float*)d_ws;
    float* pack = phi + (size_t)3 * N * F;
    float* WrT  = pack + (size_t)E * 8;
    int*   cnt  = (int*)(WrT + 5 * 3 * 128 * 4);
    int*   eid  = cnt + N;

    hipMemsetAsync(cnt, 0, (size_t)N * sizeof(int), stream);

    mlp_kernel<<<(N + 15) / 16, 256, 0, stream>>>(h_i, W1, b1, W2, b2, phi, N);
    wrt_kernel<<<8, 256, 0, stream>>>(Wr, WrT);
    build_kernel<<<(E + 255) / 256, 256, 0, stream>>>(d_ij, unit_r, nbrs, cnt,
                                                      eid, pack, E);
    gather_kernel<<<N, 128, 0, stream>>>(phi, v_i, WrT, br, cnt, eid, pack,
                                         dh, dv, N);
}

// Round 9
// 299.342 us; speedup vs baseline: 1.1872x; 1.0384x over previous
//
#include <hip/hip_runtime.h>
#include <math.h>

#define F 128
#define THREEF 384
#define N_RBF 20
#define CUTOFF 5.0f
#define CAP 64
#define TLDS_STRIDE 136   // shorts; 272 B row: 16B-aligned, ~2-way banks (free)

typedef __bf16 bf16x8 __attribute__((ext_vector_type(8)));
typedef float  f32x4  __attribute__((ext_vector_type(4)));

// ---------------------------------------------------------------------------
// Prep: cast W1 (128x128) and W2 (128x384) to bf16, k-major: WT[n][k] = W[k][n]
// so MFMA B-fragments are contiguous 16B loads.
// ---------------------------------------------------------------------------
__global__ __launch_bounds__(256) void wcast_kernel(
    const float* __restrict__ W1, const float* __restrict__ W2,
    __bf16* __restrict__ W1T, __bf16* __restrict__ W2T)
{
    const int idx = blockIdx.x * 256 + threadIdx.x;
    if (idx < 128 * 128) {
        const int n = idx >> 7, k = idx & 127;
        W1T[idx] = (__bf16)W1[k * F + n];
    }
    if (idx < 384 * 128) {
        const int n = idx >> 7, k = idx & 127;
        W2T[idx] = (__bf16)W2[k * THREEF + n];
    }
}

// ---------------------------------------------------------------------------
// MLP via bf16 MFMA (fp32 accumulate): phi = silu(h@W1+b1)@W2 + b2,
// stored as 3 planes [c][node][f]. One wave per 16 nodes, no block barriers.
// A-layout: A[m=lane&15][k=quad*8+j]; C/D: col=lane&15, row=quad*4+reg.
// ---------------------------------------------------------------------------
__global__ __launch_bounds__(256) void mlp_mfma_kernel(
    const float* __restrict__ h,      // (N,128) fp32
    const __bf16* __restrict__ W1T,   // (128n,128k)
    const float* __restrict__ b1,     // (128)
    const __bf16* __restrict__ W2T,   // (384n,128k)
    const float* __restrict__ b2,     // (384)
    float* __restrict__ phi, int N)
{
    __shared__ __bf16 t_lds[4][16 * TLDS_STRIDE];

    const int wave = threadIdx.x >> 6;
    const int lane = threadIdx.x & 63;
    const int m    = lane & 15;
    const int quad = lane >> 4;
    const int node0 = blockIdx.x * 64 + wave * 16;
    if (node0 >= N) return;

    // ---- A-frags for GEMM1: h rows, fp32 -> bf16 in registers
    bf16x8 a1[4];
    #pragma unroll
    for (int kb = 0; kb < 4; ++kb) {
        const float* hp = h + (size_t)(node0 + m) * F + kb * 32 + quad * 8;
        const float4 x0 = *(const float4*)hp;
        const float4 x1 = *(const float4*)(hp + 4);
        bf16x8 a;
        a[0] = (__bf16)x0.x; a[1] = (__bf16)x0.y;
        a[2] = (__bf16)x0.z; a[3] = (__bf16)x0.w;
        a[4] = (__bf16)x1.x; a[5] = (__bf16)x1.y;
        a[6] = (__bf16)x1.z; a[7] = (__bf16)x1.w;
        a1[kb] = a;
    }

    // ---- GEMM1: 8 col-tiles x (4 MFMAs over K=128)
    #pragma unroll
    for (int ct = 0; ct < 8; ++ct) {
        f32x4 acc = {0.0f, 0.0f, 0.0f, 0.0f};
        #pragma unroll
        for (int kb = 0; kb < 4; ++kb) {
            const bf16x8 b =
                *(const bf16x8*)(W1T + (size_t)(ct * 16 + m) * F + kb * 32 + quad * 8);
            acc = __builtin_amdgcn_mfma_f32_16x16x32_bf16(a1[kb], b, acc, 0, 0, 0);
        }
        const int col = ct * 16 + m;
        const float bb = b1[col];
        #pragma unroll
        for (int reg = 0; reg < 4; ++reg) {
            const float x = acc[reg] + bb;
            const float s = x / (1.0f + __expf(-x));          // silu, fp32
            t_lds[wave][(quad * 4 + reg) * TLDS_STRIDE + col] = (__bf16)s;
        }
    }
    // same-wave LDS ordering: compiler inserts lgkmcnt waits; no barrier needed

    // ---- A-frags for GEMM2 from LDS t
    bf16x8 a2[4];
    #pragma unroll
    for (int kb = 0; kb < 4; ++kb)
        a2[kb] = *(const bf16x8*)&t_lds[wave][m * TLDS_STRIDE + kb * 32 + quad * 8];

    // ---- GEMM2: 24 col-tiles; bias + store straight to phi planes
    #pragma unroll
    for (int ct = 0; ct < 24; ++ct) {
        f32x4 acc = {0.0f, 0.0f, 0.0f, 0.0f};
        #pragma unroll
        for (int kb = 0; kb < 4; ++kb) {
            const bf16x8 b =
                *(const bf16x8*)(W2T + (size_t)(ct * 16 + m) * F + kb * 32 + quad * 8);
            acc = __builtin_amdgcn_mfma_f32_16x16x32_bf16(a2[kb], b, acc, 0, 0, 0);
        }
        const int col   = ct * 16 + m;
        const int plane = col >> 7;
        const int fc    = col & 127;
        const float bb  = b2[col];
        float* pp = phi + (size_t)plane * N * F + fc;
        #pragma unroll
        for (int reg = 0; reg < 4; ++reg) {
            const int row = quad * 4 + reg;
            pp[(size_t)(node0 + row) * F] = acc[reg] + bb;
        }
    }
}

// ---------------------------------------------------------------------------
// WrT: chunked transpose of Wr for coalesced float4 access in gather.
// ---------------------------------------------------------------------------
__global__ __launch_bounds__(256) void wrt_kernel(
    const float* __restrict__ Wr, float* __restrict__ WrT)
{
    const int idx = blockIdx.x * 256 + threadIdx.x;   // 0 .. 1919
    if (idx >= 5 * 3 * 128) return;
    const int f  = idx & 127;
    const int c  = (idx >> 7) % 3;
    const int n4 = idx / (3 * 128);
    float4 v;
    v.x = Wr[(4 * n4 + 0) * THREEF + c * 128 + f];
    v.y = Wr[(4 * n4 + 1) * THREEF + c * 128 + f];
    v.z = Wr[(4 * n4 + 2) * THREEF + c * 128 + f];
    v.w = Wr[(4 * n4 + 3) * THREEF + c * 128 + f];
    ((float4*)WrT)[idx] = v;
}

// ---------------------------------------------------------------------------
// Build: slot via atomic; eid scatter (4B); pack linear by edge (coalesced).
// pack[e] = {s1, 2cos(x), fcut, ux, uy, uz, src_bits, 0}
// ---------------------------------------------------------------------------
__global__ __launch_bounds__(256) void build_kernel(
    const float* __restrict__ d_ij, const float* __restrict__ unit_r,
    const int* __restrict__ nbrs, int* __restrict__ cnt,
    int* __restrict__ eid, float* __restrict__ pack, int E)
{
    int e = blockIdx.x * 256 + threadIdx.x;
    if (e >= E) return;
    const int2 nb = ((const int2*)nbrs)[e];
    const int dst = nb.x;
    const int src = nb.y;
    const int slot = atomicAdd(&cnt[dst], 1);
    if (slot < CAP) eid[dst * CAP + slot] = e;

    const float d = d_ij[e];
    const float x = (float)M_PI * d * (1.0f / CUTOFF);
    float sx, cx;
    __sincosf(x, &sx, &cx);
    const float fcut = (d < CUTOFF) ? 0.5f * (cx + 1.0f) : 0.0f;
    float4 q0, q1;
    q0.x = sx * fcut / d;     // rbff_1; recurrence preserves the fcut/d scale
    q0.y = 2.0f * cx;
    q0.z = fcut;
    q0.w = unit_r[3 * e + 0];
    q1.x = unit_r[3 * e + 1];
    q1.y = unit_r[3 * e + 2];
    q1.z = __int_as_float(src);
    q1.w = 0.0f;
    float4* pk = (float4*)(pack + (size_t)e * 8);
    pk[0] = q0;
    pk[1] = q1;
}

// ---------------------------------------------------------------------------
// Gather (R5/R8 converged structure): block = 1 node x 128 threads.
// ---------------------------------------------------------------------------
__global__ __launch_bounds__(128) void gather_kernel(
    const float* __restrict__ phi,       // 3 planes of (N,128)
    const float* __restrict__ v_i,       // (N,128,3)
    const float* __restrict__ WrT,       // (5,3,128,4) chunked transpose
    const float* __restrict__ br,        // (384)
    const int*   __restrict__ cnt,       // (N)
    const int*   __restrict__ eid,       // (N,CAP)
    const float* __restrict__ pack,      // (E,8)
    float* __restrict__ dh,              // (N,128)
    float* __restrict__ dv,              // (N,128,3)
    int N)
{
    const int node = blockIdx.x;
    const int f    = threadIdx.x;

    const float br0 = br[f], br1 = br[f + 128], br2 = br[f + 256];

    const int deg0 = cnt[node];
    const int deg  = deg0 < CAP ? deg0 : CAP;
    const int* my_eid = eid + node * CAP;

    const float* phi0 = phi;
    const float* phi1 = phi + (size_t)N * F;
    const float* phi2 = phi + (size_t)2 * N * F;
    const float4* wT  = (const float4*)WrT;   // wT[(n4*3 + c)*128 + f]

    float dh_acc = 0.0f, dv0 = 0.0f, dv1 = 0.0f, dv2 = 0.0f;

    for (int i = 0; i < deg; ++i) {
        const int e = __builtin_amdgcn_readfirstlane(my_eid[i]);
        const float* pk = pack + (size_t)e * 8;
        const float s1   = pk[0];
        const float twoc = pk[1];
        const float fcut = pk[2];
        const float ux   = pk[3];
        const float uy   = pk[4];
        const float uz   = pk[5];
        const int src = __builtin_amdgcn_readfirstlane(__float_as_int(pk[6]));

        float a0 = br0 * fcut, a1 = br1 * fcut, a2 = br2 * fcut;
        float rp = 0.0f, rc = s1;
        #pragma unroll
        for (int n4 = 0; n4 < 5; ++n4) {
            const float4 w0 = wT[(n4 * 3 + 0) * 128 + f];
            const float4 w1 = wT[(n4 * 3 + 1) * 128 + f];
            const float4 w2 = wT[(n4 * 3 + 2) * 128 + f];
            #pragma unroll
            for (int k = 0; k < 4; ++k) {
                const float wa = ((const float*)&w0)[k];
                const float wb = ((const float*)&w1)[k];
                const float wc = ((const float*)&w2)[k];
                a0 = fmaf(rc, wa, a0);
                a1 = fmaf(rc, wb, a1);
                a2 = fmaf(rc, wc, a2);
                const float rn = fmaf(twoc, rc, -rp);
                rp = rc;
                rc = rn;
            }
        }

        const float f1 = phi0[(size_t)src * F + f] * a0;
        const float f2 = phi1[(size_t)src * F + f] * a1;
        const float f3 = phi2[(size_t)src * F + f] * a2;

        dh_acc += f3;

        const float* vs = v_i + (size_t)src * THREEF + 3 * f;
        dv0 = fmaf(f1, ux, fmaf(f2, vs[0], dv0));
        dv1 = fmaf(f1, uy, fmaf(f2, vs[1], dv1));
        dv2 = fmaf(f1, uz, fmaf(f2, vs[2], dv2));
    }

    dh[(size_t)node * F + f] = dh_acc;
    float* dvp = dv + (size_t)node * THREEF + 3 * f;
    dvp[0] = dv0;
    dvp[1] = dv1;
    dvp[2] = dv2;
}

extern "C" void kernel_launch(void* const* d_in, const int* in_sizes, int n_in,
                              void* d_out, int out_size, void* d_ws, size_t ws_size,
                              hipStream_t stream) {
    const float* h_i    = (const float*)d_in[0];
    const float* v_i    = (const float*)d_in[1];
    const float* d_ij   = (const float*)d_in[2];
    const float* unit_r = (const float*)d_in[3];
    const int*   nbrs   = (const int*)  d_in[4];
    const float* W1     = (const float*)d_in[5];
    const float* b1     = (const float*)d_in[6];
    const float* W2     = (const float*)d_in[7];
    const float* b2     = (const float*)d_in[8];
    const float* Wr     = (const float*)d_in[9];
    const float* br     = (const float*)d_in[10];

    const int N = in_sizes[0] / F;       // 20000
    const int E = in_sizes[2];           // 320000

    float* dh = (float*)d_out;              // (N,128)
    float* dv = dh + (size_t)N * F;         // (N,128,3)

    // workspace: phi | pack | WrT | cnt | eid | W1T | W2T  (all 16B aligned)
    float*  phi  = (float*)d_ws;                         // 3*N*128
    float*  pack = phi + (size_t)3 * N * F;              // E*8
    float*  WrT  = pack + (size_t)E * 8;                 // 7680
    int*    cnt  = (int*)(WrT + 5 * 3 * 128 * 4);        // N
    int*    eid  = cnt + N;                              // N*CAP
    __bf16* W1T  = (__bf16*)(eid + (size_t)N * CAP);     // 128*128
    __bf16* W2T  = W1T + 128 * 128;                      // 384*128

    hipMemsetAsync(cnt, 0, (size_t)N * sizeof(int), stream);

    wcast_kernel<<<192, 256, 0, stream>>>(W1, W2, W1T, W2T);
    mlp_mfma_kernel<<<(N + 63) / 64, 256, 0, stream>>>(h_i, W1T, b1, W2T, b2,
                                                       phi, N);
    wrt_kernel<<<8, 256, 0, stream>>>(Wr, WrT);
    build_kernel<<<(E + 255) / 256, 256, 0, stream>>>(d_ij, unit_r, nbrs, cnt,
                                                      eid, pack, E);
    gather_kernel<<<N, 128, 0, stream>>>(phi, v_i, WrT, br, cnt, eid, pack,
                                         dh, dv, N);
}

// Round 10
// 294.922 us; speedup vs baseline: 1.2050x; 1.0150x over previous
//
#include <hip/hip_runtime.h>
#include <math.h>

#define F 128
#define THREEF 384
#define N_RBF 20
#define CUTOFF 5.0f
#define CAP 64
#define TLDS_STRIDE 136   // shorts; 272 B row: 16B-aligned, ~2-way banks (free)

typedef __bf16 bf16x8 __attribute__((ext_vector_type(8)));
typedef float  f32x4  __attribute__((ext_vector_type(4)));

// ---------------------------------------------------------------------------
// Prep (fused, block-range sliced):
//   blocks [0, EB)        : build — CSR slot via atomic, pack written directly
//                           at (dst,slot) so gather reads contiguously
//   blocks [EB, EB+256)   : wcast — W1,W2 -> bf16 k-major
//   blocks [EB+256, +8)   : wrt — chunked transpose of Wr for gather
// pack row = {s1, 2cos(x), fcut, ux, uy, uz, src_bits, 0}
// ---------------------------------------------------------------------------
__global__ __launch_bounds__(256) void prep_kernel(
    const float* __restrict__ d_ij, const float* __restrict__ unit_r,
    const int* __restrict__ nbrs,
    const float* __restrict__ W1, const float* __restrict__ W2,
    const float* __restrict__ Wr,
    int* __restrict__ cnt, float* __restrict__ pack,
    __bf16* __restrict__ W1T, __bf16* __restrict__ W2T,
    float* __restrict__ WrT, int E, int EB)
{
    const int tid = threadIdx.x;
    const int b   = blockIdx.x;

    if (b < EB) {                       // ---- build
        const int e = b * 256 + tid;
        if (e >= E) return;
        const int2 nb = ((const int2*)nbrs)[e];
        const int dst = nb.x;
        const int src = nb.y;
        const int slot = atomicAdd(&cnt[dst], 1);
        if (slot >= CAP) return;

        const float d = d_ij[e];
        const float x = (float)M_PI * d * (1.0f / CUTOFF);
        float sx, cx;
        __sincosf(x, &sx, &cx);
        const float fcut = (d < CUTOFF) ? 0.5f * (cx + 1.0f) : 0.0f;
        float4 q0, q1;
        q0.x = sx * fcut / d;           // rbff_1; recurrence keeps fcut/d scale
        q0.y = 2.0f * cx;
        q0.z = fcut;
        q0.w = unit_r[3 * e + 0];
        q1.x = unit_r[3 * e + 1];
        q1.y = unit_r[3 * e + 2];
        q1.z = __int_as_float(src);
        q1.w = 0.0f;
        float4* pk = (float4*)(pack + ((size_t)dst * CAP + slot) * 8);
        pk[0] = q0;
        pk[1] = q1;
    } else if (b < EB + 256) {          // ---- wcast
        const int idx = (b - EB) * 256 + tid;
        if (idx < 128 * 128) {
            const int n = idx >> 7, k = idx & 127;
            W1T[idx] = (__bf16)W1[k * F + n];
        }
        if (idx < 384 * 128) {
            const int n = idx >> 7, k = idx & 127;
            W2T[idx] = (__bf16)W2[k * THREEF + n];
        }
    } else {                            // ---- wrt
        const int idx = (b - EB - 256) * 256 + tid;   // 0..1919
        if (idx >= 5 * 3 * 128) return;
        const int f  = idx & 127;
        const int c  = (idx >> 7) % 3;
        const int n4 = idx / (3 * 128);
        float4 v;
        v.x = Wr[(4 * n4 + 0) * THREEF + c * 128 + f];
        v.y = Wr[(4 * n4 + 1) * THREEF + c * 128 + f];
        v.z = Wr[(4 * n4 + 2) * THREEF + c * 128 + f];
        v.w = Wr[(4 * n4 + 3) * THREEF + c * 128 + f];
        ((float4*)WrT)[idx] = v;
    }
}

// ---------------------------------------------------------------------------
// MLP via bf16 MFMA (fp32 accumulate): phi = silu(h@W1+b1)@W2 + b2,
// stored as 3 planes [c][node][f]. One wave per 16 nodes (R9, verified).
// ---------------------------------------------------------------------------
__global__ __launch_bounds__(256) void mlp_mfma_kernel(
    const float* __restrict__ h,      // (N,128) fp32
    const __bf16* __restrict__ W1T,   // (128n,128k)
    const float* __restrict__ b1,     // (128)
    const __bf16* __restrict__ W2T,   // (384n,128k)
    const float* __restrict__ b2,     // (384)
    float* __restrict__ phi, int N)
{
    __shared__ __bf16 t_lds[4][16 * TLDS_STRIDE];

    const int wave = threadIdx.x >> 6;
    const int lane = threadIdx.x & 63;
    const int m    = lane & 15;
    const int quad = lane >> 4;
    const int node0 = blockIdx.x * 64 + wave * 16;
    if (node0 >= N) return;

    bf16x8 a1[4];
    #pragma unroll
    for (int kb = 0; kb < 4; ++kb) {
        const float* hp = h + (size_t)(node0 + m) * F + kb * 32 + quad * 8;
        const float4 x0 = *(const float4*)hp;
        const float4 x1 = *(const float4*)(hp + 4);
        bf16x8 a;
        a[0] = (__bf16)x0.x; a[1] = (__bf16)x0.y;
        a[2] = (__bf16)x0.z; a[3] = (__bf16)x0.w;
        a[4] = (__bf16)x1.x; a[5] = (__bf16)x1.y;
        a[6] = (__bf16)x1.z; a[7] = (__bf16)x1.w;
        a1[kb] = a;
    }

    #pragma unroll
    for (int ct = 0; ct < 8; ++ct) {
        f32x4 acc = {0.0f, 0.0f, 0.0f, 0.0f};
        #pragma unroll
        for (int kb = 0; kb < 4; ++kb) {
            const bf16x8 b =
                *(const bf16x8*)(W1T + (size_t)(ct * 16 + m) * F + kb * 32 + quad * 8);
            acc = __builtin_amdgcn_mfma_f32_16x16x32_bf16(a1[kb], b, acc, 0, 0, 0);
        }
        const int col = ct * 16 + m;
        const float bb = b1[col];
        #pragma unroll
        for (int reg = 0; reg < 4; ++reg) {
            const float x = acc[reg] + bb;
            const float s = x / (1.0f + __expf(-x));
            t_lds[wave][(quad * 4 + reg) * TLDS_STRIDE + col] = (__bf16)s;
        }
    }

    bf16x8 a2[4];
    #pragma unroll
    for (int kb = 0; kb < 4; ++kb)
        a2[kb] = *(const bf16x8*)&t_lds[wave][m * TLDS_STRIDE + kb * 32 + quad * 8];

    #pragma unroll
    for (int ct = 0; ct < 24; ++ct) {
        f32x4 acc = {0.0f, 0.0f, 0.0f, 0.0f};
        #pragma unroll
        for (int kb = 0; kb < 4; ++kb) {
            const bf16x8 b =
                *(const bf16x8*)(W2T + (size_t)(ct * 16 + m) * F + kb * 32 + quad * 8);
            acc = __builtin_amdgcn_mfma_f32_16x16x32_bf16(a2[kb], b, acc, 0, 0, 0);
        }
        const int col   = ct * 16 + m;
        const int plane = col >> 7;
        const int fc    = col & 127;
        const float bb  = b2[col];
        float* pp = phi + (size_t)plane * N * F + fc;
        #pragma unroll
        for (int reg = 0; reg < 4; ++reg) {
            const int row = quad * 4 + reg;
            pp[(size_t)(node0 + row) * F] = acc[reg] + bb;
        }
    }
}

// ---------------------------------------------------------------------------
// Gather: 256 threads = 2 nodes/block. Per-node pack block staged into LDS
// once (coalesced float4); per-edge uniforms come from LDS broadcast, so no
// vmcnt-draining readfirstlane — phi/v gathers pipeline across edges.
// ---------------------------------------------------------------------------
__global__ __launch_bounds__(256) void gather_kernel(
    const float* __restrict__ phi,       // 3 planes of (N,128)
    const float* __restrict__ v_i,       // (N,128,3)
    const float* __restrict__ WrT,       // (5,3,128,4) chunked transpose
    const float* __restrict__ br,        // (384)
    const int*   __restrict__ cnt,       // (N)
    const float* __restrict__ pack,      // (N,CAP,8)
    float* __restrict__ dh,              // (N,128)
    float* __restrict__ dv,              // (N,128,3)
    int N)
{
    __shared__ float4 s_pack[2][CAP * 2];   // 4 KB

    const int tid  = threadIdx.x;
    const int half = tid >> 7;
    const int f    = tid & 127;
    const int node = blockIdx.x * 2 + half;

    const int deg0 = cnt[node];
    const int deg  = deg0 < CAP ? deg0 : CAP;

    {   // stage this node's pack rows: deg*2 float4s, coalesced
        const float4* src = (const float4*)(pack + (size_t)node * CAP * 8);
        if (f < 2 * deg) s_pack[half][f] = src[f];
    }
    __syncthreads();

    const float br0 = br[f], br1 = br[f + 128], br2 = br[f + 256];

    const float* phi0 = phi;
    const float* phi1 = phi + (size_t)N * F;
    const float* phi2 = phi + (size_t)2 * N * F;
    const float4* wT  = (const float4*)WrT;   // wT[(n4*3 + c)*128 + f]

    float dh_acc = 0.0f, dv0 = 0.0f, dv1 = 0.0f, dv2 = 0.0f;

    for (int i = 0; i < deg; ++i) {
        const float* q = (const float*)&s_pack[half][2 * i];
        const float s1   = q[0];
        const float twoc = q[1];
        const float fcut = q[2];
        const float ux   = q[3];
        const float uy   = q[4];
        const float uz   = q[5];
        // LDS value -> SGPR: only lgkmcnt wait, global-load queue stays full
        const int src = __builtin_amdgcn_readfirstlane(__float_as_int(q[6]));

        float a0 = br0 * fcut, a1 = br1 * fcut, a2 = br2 * fcut;
        float rp = 0.0f, rc = s1;
        #pragma unroll
        for (int n4 = 0; n4 < 5; ++n4) {
            const float4 w0 = wT[(n4 * 3 + 0) * 128 + f];
            const float4 w1 = wT[(n4 * 3 + 1) * 128 + f];
            const float4 w2 = wT[(n4 * 3 + 2) * 128 + f];
            #pragma unroll
            for (int k = 0; k < 4; ++k) {
                const float wa = ((const float*)&w0)[k];
                const float wb = ((const float*)&w1)[k];
                const float wc = ((const float*)&w2)[k];
                a0 = fmaf(rc, wa, a0);
                a1 = fmaf(rc, wb, a1);
                a2 = fmaf(rc, wc, a2);
                const float rn = fmaf(twoc, rc, -rp);
                rp = rc;
                rc = rn;
            }
        }

        const float f1 = phi0[(size_t)src * F + f] * a0;
        const float f2 = phi1[(size_t)src * F + f] * a1;
        const float f3 = phi2[(size_t)src * F + f] * a2;

        dh_acc += f3;

        const float* vs = v_i + (size_t)src * THREEF + 3 * f;
        dv0 = fmaf(f1, ux, fmaf(f2, vs[0], dv0));
        dv1 = fmaf(f1, uy, fmaf(f2, vs[1], dv1));
        dv2 = fmaf(f1, uz, fmaf(f2, vs[2], dv2));
    }

    dh[(size_t)node * F + f] = dh_acc;
    float* dvp = dv + (size_t)node * THREEF + 3 * f;
    dvp[0] = dv0;
    dvp[1] = dv1;
    dvp[2] = dv2;
}

extern "C" void kernel_launch(void* const* d_in, const int* in_sizes, int n_in,
                              void* d_out, int out_size, void* d_ws, size_t ws_size,
                              hipStream_t stream) {
    const float* h_i    = (const float*)d_in[0];
    const float* v_i    = (const float*)d_in[1];
    const float* d_ij   = (const float*)d_in[2];
    const float* unit_r = (const float*)d_in[3];
    const int*   nbrs   = (const int*)  d_in[4];
    const float* W1     = (const float*)d_in[5];
    const float* b1     = (const float*)d_in[6];
    const float* W2     = (const float*)d_in[7];
    const float* b2     = (const float*)d_in[8];
    const float* Wr     = (const float*)d_in[9];
    const float* br     = (const float*)d_in[10];

    const int N = in_sizes[0] / F;       // 20000
    const int E = in_sizes[2];           // 320000

    float* dh = (float*)d_out;              // (N,128)
    float* dv = dh + (size_t)N * F;         // (N,128,3)

    // workspace: phi (3NF) | pack (N*CAP*8) | WrT | cnt | W1T | W2T
    float*  phi  = (float*)d_ws;                           // 30.7 MB
    float*  pack = phi + (size_t)3 * N * F;                // 41 MB
    float*  WrT  = pack + (size_t)N * CAP * 8;             // 30 KB
    int*    cnt  = (int*)(WrT + 5 * 3 * 128 * 4);          // 80 KB
    __bf16* W1T  = (__bf16*)(cnt + N);                     // 32 KB
    __bf16* W2T  = W1T + 128 * 128;                        // 96 KB

    const int EB = (E + 255) / 256;      // 1250 build blocks

    hipMemsetAsync(cnt, 0, (size_t)N * sizeof(int), stream);

    prep_kernel<<<EB + 256 + 8, 256, 0, stream>>>(
        d_ij, unit_r, nbrs, W1, W2, Wr, cnt, pack, W1T, W2T, WrT, E, EB);
    mlp_mfma_kernel<<<(N + 63) / 64, 256, 0, stream>>>(h_i, W1T, b1, W2T, b2,
                                                       phi, N);
    gather_kernel<<<N / 2, 256, 0, stream>>>(phi, v_i, WrT, br, cnt, pack,
                                             dh, dv, N);
}